// Round 2
// baseline (546.732 us; speedup 1.0000x reference)
//
#include <hip/hip_runtime.h>
#include <stdint.h>

typedef unsigned short u16;
typedef unsigned int   u32;

#define B_SZ  32
#define CIN   256
#define NPIX  3136      // 56*56
#define COUT  256
#define HID   64
#define NBANK 4
#define BANK_SZ 589824  // COUT*CIN*9 elements per bank (fp32)
#define WF_N  18874368  // premixed elements per half: 32*16*9*8*512

typedef short bf16x8 __attribute__((ext_vector_type(8)));
typedef float f32x4  __attribute__((ext_vector_type(4)));

struct __align__(16) U4 { u32 x, y, z, w; };
struct __align__(16) F4 { float x, y, z, w; };

__device__ __forceinline__ float bf2f(u16 u) {
    union { u32 i; float f; } v; v.i = ((u32)u) << 16; return v.f;
}
__device__ __forceinline__ u16 f2bf(float f) {
    union { float f; u32 i; } v; v.f = f;
    u32 u = v.i;
    return (u16)((u + 0x7FFFu + ((u >> 16) & 1u)) >> 16);   // RNE
}

// ---------------------------------------------------------------- mean ----
__global__ __launch_bounds__(64) void k_mean(const float* __restrict__ x,
                                             float* __restrict__ vout) {
    int bc = blockIdx.x;
    const F4* p = (const F4*)(x + (size_t)bc * NPIX);
    float s = 0.f;
    for (int o = threadIdx.x; o < 784; o += 64) {   // 784*4 = 3136
        F4 u = p[o];
        s += u.x + u.y + u.z + u.w;
    }
    #pragma unroll
    for (int off = 32; off > 0; off >>= 1) s += __shfl_down(s, off, 64);
    if (threadIdx.x == 0) vout[bc] = s * (1.0f / 3136.0f);
}

// -------------------------------------------------------------- router ----
__global__ __launch_bounds__(64) void k_router(const float* __restrict__ v,
        const float* __restrict__ fc1w, const float* __restrict__ fc1b,
        const float* __restrict__ fc2w, const float* __restrict__ fc2b,
        float* __restrict__ aout) {
    int b = blockIdx.x, j = threadIdx.x;
    __shared__ float hl[HID];
    __shared__ float lg[NBANK];
    const float* vb = v + b * CIN;
    float acc = fc1b[j];
    const F4* wrow = (const F4*)(fc1w + j * CIN);
    for (int o = 0; o < 64; ++o) {
        F4 u = wrow[o];
        acc += vb[o * 4 + 0] * u.x + vb[o * 4 + 1] * u.y
             + vb[o * 4 + 2] * u.z + vb[o * 4 + 3] * u.w;
    }
    hl[j] = acc > 0.f ? acc : 0.f;
    __syncthreads();
    if (j < NBANK) {
        float l = fc2b[j];
        for (int t = 0; t < HID; ++t) l += hl[t] * fc2w[j * HID + t];
        lg[j] = l;
    }
    __syncthreads();
    if (j == 0) {
        float m = lg[0];
        for (int k = 1; k < NBANK; ++k) m = fmaxf(m, lg[k]);
        float e[NBANK], se = 0.f;
        for (int k = 0; k < NBANK; ++k) { e[k] = expf(lg[k] - m); se += e[k]; }
        for (int k = 0; k < NBANK; ++k) aout[b * NBANK + k] = e[k] / se;
    }
}

// -------------------------------------------------------------- premix ----
// Wdyn = sum_k a[b][k]*bank[k] in fp32, split into bf16 hi/lo, stored in
// MFMA-A layout: wf[half][b][cof16][t][cis32][lane][8]
//   co = cof16*16 + (lane&15); ci = cis32*32 + (lane>>4)*8 + j; t = ty*3+tx
// grid = 256 blocks (cof16 in [0,16), cis16 in [0,16)), 256 threads.
#define PM_PAD 145   // 144 floats per row + 1 pad
__global__ __launch_bounds__(256) void k_premix(const float* __restrict__ bank,
        const float* __restrict__ aws, u16* __restrict__ wf) {
    int cof   = blockIdx.x >> 4;   // 0..15
    int cis16 = blockIdx.x & 15;   // 0..15 (16-ci granule)
    __shared__ float lw[64 * PM_PAD];   // [k*16+co_l][ci_l16*9+t]
    for (int idx = threadIdx.x; idx < 64 * 144; idx += 256) {
        int s = idx / 144;             // k*16 + co_l
        int e = idx - s * 144;         // ci_l16*9 + t
        int k = s >> 4, co_l = s & 15;
        lw[s * PM_PAD + e] =
            bank[(size_t)(k * COUT + cof * 16 + co_l) * (CIN * 9) + cis16 * 144 + e];
    }
    __syncthreads();
    const int cis   = cis16 >> 1;
    const int qbase = (cis16 & 1) * 2;     // lane quads covered: qbase..qbase+1
    for (int b = 0; b < B_SZ; ++b) {
        float a0 = aws[b * 4 + 0], a1 = aws[b * 4 + 1];
        float a2 = aws[b * 4 + 2], a3 = aws[b * 4 + 3];
        for (int o = threadIdx.x; o < 288; o += 256) {   // 9 taps * 32 half-lanes
            int t  = o >> 5;
            int hlane = o & 31;
            int lane  = qbase * 16 + hlane;   // 32 lanes of this half
            int m = lane & 15, q = lane >> 4;
            int q_loc = q - qbase;            // 0..1
            u16 ph[8], plo[8];
            #pragma unroll
            for (int jj = 0; jj < 8; ++jj) {
                int ee = (q_loc * 8 + jj) * 9 + t;
                float w = a0 * lw[(0 * 16 + m) * PM_PAD + ee]
                        + a1 * lw[(1 * 16 + m) * PM_PAD + ee]
                        + a2 * lw[(2 * 16 + m) * PM_PAD + ee]
                        + a3 * lw[(3 * 16 + m) * PM_PAD + ee];
                u16 h = f2bf(w);
                ph[jj]  = h;
                plo[jj] = f2bf(w - bf2f(h));
            }
            size_t off = ((((size_t)b * 16 + cof) * 9 + t) * 8 + cis) * 512
                       + (size_t)lane * 8;
            U4 uh, ul;
            uh.x = (u32)ph[0] | ((u32)ph[1] << 16);
            uh.y = (u32)ph[2] | ((u32)ph[3] << 16);
            uh.z = (u32)ph[4] | ((u32)ph[5] << 16);
            uh.w = (u32)ph[6] | ((u32)ph[7] << 16);
            ul.x = (u32)plo[0] | ((u32)plo[1] << 16);
            ul.y = (u32)plo[2] | ((u32)plo[3] << 16);
            ul.z = (u32)plo[4] | ((u32)plo[5] << 16);
            ul.w = (u32)plo[6] | ((u32)plo[7] << 16);
            *(U4*)(wf + off)        = uh;
            *(U4*)(wf + WF_N + off) = ul;
        }
    }
}

// ---------------------------------------------------------------- conv ----
// Implicit GEMM, split-bf16 3-pass: y ~= wh*xh + wh*xl + wl*xh (fp32 acc).
// Block = 256 thr = 4 waves (2x2 over co x pix). CO_TILE=128, PIX_TILE=128.
// LDS: xh/xl planes [6 rows][58 cols][32 ci] bf16, staged from fp32 x.
template<bool PRE>
__global__ __launch_bounds__(256, 2) void k_conv(const float* __restrict__ x,
        const u16* __restrict__ wh_t,     // premixed hi (PRE only); lo at +WF_N
        const float* __restrict__ bank,   // raw banks (fallback only)
        const float* __restrict__ aws,
        float* __restrict__ out) {
    const int pt    = blockIdx.x;   // 0..24 pixel tile (128 pixels)
    const int coblk = blockIdx.y;   // 0..1  co half (128 co)
    const int b     = blockIdx.z;   // 0..31

    const int tid  = threadIdx.x;
    const int wave = tid >> 6;
    const int lane = tid & 63;
    const int wm = wave >> 1, wn = wave & 1;

    __shared__ u16 xs[2][6 * 58 * 32];   // hi/lo planes, 22272 B each

    const int pix0 = pt * 128;
    const int h0   = pix0 / 56;
    const int rlo  = h0 - 1;

    const float* xb = x + (size_t)b * CIN * NPIX;

    int bbase[4], pl[4];
    #pragma unroll
    for (int nf = 0; nf < 4; ++nf) {
        int p = pix0 + wn * 64 + nf * 16 + (lane & 15);
        pl[nf] = p;
        int pc = p < NPIX ? p : NPIX - 1;
        int hp = pc / 56, wp = pc - (pc / 56) * 56;
        bbase[nf] = ((hp - h0) * 58 + wp) * 64 + (lane >> 4) * 16;   // bytes
    }

    const int cof_base = coblk * 8 + wm * 4;
    float a0 = 0.f, a1 = 0.f, a2 = 0.f, a3 = 0.f;
    if (!PRE) {
        a0 = aws[b * 4 + 0]; a1 = aws[b * 4 + 1];
        a2 = aws[b * 4 + 2]; a3 = aws[b * 4 + 3];
    }

    f32x4 acc[4][4];
    #pragma unroll
    for (int i = 0; i < 4; ++i)
        #pragma unroll
        for (int j = 0; j < 4; ++j) { f32x4 z = {0.f, 0.f, 0.f, 0.f}; acc[i][j] = z; }

    for (int cis = 0; cis < 8; ++cis) {
        const int ci0 = cis * 32;
        __syncthreads();
        // ---- stage + split: fp32 x -> bf16 hi/lo planes ----
        for (int idx = tid; idx < 1392; idx += 256) {   // 6*58 pos x 4 octets
            int oct = idx / 348;
            int rc  = idx - oct * 348;
            int row = rc / 58, col = rc - row * 58;
            int hin = rlo + row, win = col - 1;
            U4 uh; uh.x = 0; uh.y = 0; uh.z = 0; uh.w = 0;
            U4 ul = uh;
            if (hin >= 0 && hin < 56 && win >= 0 && win < 56) {
                const float* g = xb + (size_t)(ci0 + oct * 8) * NPIX + hin * 56 + win;
                u16 eh[8], el[8];
                #pragma unroll
                for (int i = 0; i < 8; ++i) {
                    float v = g[(size_t)i * NPIX];
                    u16 h = f2bf(v);
                    eh[i] = h;
                    el[i] = f2bf(v - bf2f(h));
                }
                uh.x = (u32)eh[0] | ((u32)eh[1] << 16);
                uh.y = (u32)eh[2] | ((u32)eh[3] << 16);
                uh.z = (u32)eh[4] | ((u32)eh[5] << 16);
                uh.w = (u32)eh[6] | ((u32)eh[7] << 16);
                ul.x = (u32)el[0] | ((u32)el[1] << 16);
                ul.y = (u32)el[2] | ((u32)el[3] << 16);
                ul.z = (u32)el[4] | ((u32)el[5] << 16);
                ul.w = (u32)el[6] | ((u32)el[7] << 16);
            }
            *(U4*)(&xs[0][rc * 32 + oct * 8]) = uh;
            *(U4*)(&xs[1][rc * 32 + oct * 8]) = ul;
        }
        __syncthreads();

        #pragma unroll
        for (int t = 0; t < 9; ++t) {
            const int ty = t / 3, tx = t - (t / 3) * 3;
            bf16x8 ah[4], al[4];
            if (PRE) {
                #pragma unroll
                for (int mf = 0; mf < 4; ++mf) {
                    size_t off = ((((size_t)b * 16 + cof_base + mf) * 9 + t) * 8 + cis) * 512
                               + (size_t)lane * 8;
                    ah[mf] = *(const bf16x8*)(wh_t + off);
                    al[mf] = *(const bf16x8*)(wh_t + WF_N + off);
                }
            } else {
                #pragma unroll
                for (int mf = 0; mf < 4; ++mf) {
                    int co = coblk * 128 + wm * 64 + mf * 16 + (lane & 15);
                    int q = lane >> 4;
                    u16 ph[8], plo[8];
                    #pragma unroll
                    for (int jj = 0; jj < 8; ++jj) {
                        int ci = ci0 + q * 8 + jj;
                        size_t base = ((size_t)co * CIN + ci) * 9 + t;
                        float w = a0 * bank[base]
                                + a1 * bank[base + BANK_SZ]
                                + a2 * bank[base + 2 * BANK_SZ]
                                + a3 * bank[base + 3 * BANK_SZ];
                        u16 h = f2bf(w);
                        ph[jj]  = h;
                        plo[jj] = f2bf(w - bf2f(h));
                    }
                    union { U4 u; bf16x8 v; } pu;
                    pu.u.x = (u32)ph[0] | ((u32)ph[1] << 16);
                    pu.u.y = (u32)ph[2] | ((u32)ph[3] << 16);
                    pu.u.z = (u32)ph[4] | ((u32)ph[5] << 16);
                    pu.u.w = (u32)ph[6] | ((u32)ph[7] << 16);
                    ah[mf] = pu.v;
                    pu.u.x = (u32)plo[0] | ((u32)plo[1] << 16);
                    pu.u.y = (u32)plo[2] | ((u32)plo[3] << 16);
                    pu.u.z = (u32)plo[4] | ((u32)plo[5] << 16);
                    pu.u.w = (u32)plo[6] | ((u32)plo[7] << 16);
                    al[mf] = pu.v;
                }
            }
            const int toff = (ty * 58 + tx) * 64;   // bytes
            #pragma unroll
            for (int nf = 0; nf < 4; ++nf) {
                bf16x8 bh = *(const bf16x8*)((const char*)&xs[0][0] + bbase[nf] + toff);
                bf16x8 bl = *(const bf16x8*)((const char*)&xs[1][0] + bbase[nf] + toff);
                #pragma unroll
                for (int mf = 0; mf < 4; ++mf) {
                    acc[mf][nf] = __builtin_amdgcn_mfma_f32_16x16x32_bf16(
                        ah[mf], bh, acc[mf][nf], 0, 0, 0);
                    acc[mf][nf] = __builtin_amdgcn_mfma_f32_16x16x32_bf16(
                        ah[mf], bl, acc[mf][nf], 0, 0, 0);
                    acc[mf][nf] = __builtin_amdgcn_mfma_f32_16x16x32_bf16(
                        al[mf], bh, acc[mf][nf], 0, 0, 0);
                }
            }
        }
    }

    // ---- epilogue: C/D layout col(pixel)=lane&15, row(co)=(lane>>4)*4+r ----
    float* ob = out + (size_t)b * COUT * NPIX;
    #pragma unroll
    for (int mf = 0; mf < 4; ++mf) {
        int cobase = coblk * 128 + wm * 64 + mf * 16 + (lane >> 4) * 4;
        #pragma unroll
        for (int nf = 0; nf < 4; ++nf) {
            int p = pl[nf];
            if (p < NPIX) {
                #pragma unroll
                for (int r = 0; r < 4; ++r)
                    ob[(size_t)(cobase + r) * NPIX + p] = acc[mf][nf][r];
            }
        }
    }
}

// -------------------------------------------------------------- launch ----
extern "C" void kernel_launch(void* const* d_in, const int* in_sizes, int n_in,
                              void* d_out, int out_size, void* d_ws, size_t ws_size,
                              hipStream_t stream) {
    const float* x    = (const float*)d_in[0];
    const float* bank = (const float*)d_in[1];
    const float* fc1w = (const float*)d_in[2];
    const float* fc1b = (const float*)d_in[3];
    const float* fc2w = (const float*)d_in[4];
    const float* fc2b = (const float*)d_in[5];
    float* out = (float*)d_out;

    float* a_ws = (float*)d_ws;                 // 128 floats @ 0
    float* v_ws = (float*)d_ws + 128;           // 8192 floats @ 512B
    u16*   wf   = (u16*)((char*)d_ws + 65536);  // 2 x 37.75 MB premixed hi/lo

    k_mean<<<dim3(B_SZ * CIN), dim3(64), 0, stream>>>(x, v_ws);
    k_router<<<dim3(B_SZ), dim3(64), 0, stream>>>(v_ws, fc1w, fc1b, fc2w, fc2b, a_ws);

    const bool pre = ws_size >= (size_t)65536 + (size_t)WF_N * 2 * sizeof(u16);
    dim3 grid(25, 2, B_SZ);
    if (pre) {
        k_premix<<<dim3(256), dim3(256), 0, stream>>>(bank, a_ws, wf);
        k_conv<true><<<grid, dim3(256), 0, stream>>>(x, wf, bank, a_ws, out);
    } else {
        k_conv<false><<<grid, dim3(256), 0, stream>>>(x, wf, bank, a_ws, out);
    }
}